// Round 5
// baseline (419.586 us; speedup 1.0000x reference)
//
#include <hip/hip_runtime.h>

#define NN 100000
#define NE 1280000
#define K_FEAT 500
#define K_TEXT 384
#define KP 512
#define H 64
#define BM 128
#define SCAN_BLOCKS 100
#define NODES_PER_SCAN 1000

typedef unsigned short ushort_t;
typedef __attribute__((ext_vector_type(8))) short bf16x8;
typedef __attribute__((ext_vector_type(4))) float f32x4;

template <int V> struct IC { static constexpr int value = V; };

__device__ __forceinline__ ushort_t f2bf(float f) {
    union { float f; unsigned int u; } v; v.f = f;
    unsigned int r = (v.u + 0x7FFFu + ((v.u >> 16) & 1u)) >> 16;  // RNE
    return (ushort_t)r;
}

// pack 8 f32 -> 8 bf16 via hardware cvt_pk (RNE)
__device__ __forceinline__ bf16x8 cvt8(float4 a, float4 b) {
    union { bf16x8 v; unsigned int w[4]; } u;
    asm("v_cvt_pk_bf16_f32 %0, %1, %2" : "=v"(u.w[0]) : "v"(a.x), "v"(a.y));
    asm("v_cvt_pk_bf16_f32 %0, %1, %2" : "=v"(u.w[1]) : "v"(a.z), "v"(a.w));
    asm("v_cvt_pk_bf16_f32 %0, %1, %2" : "=v"(u.w[2]) : "v"(b.x), "v"(b.y));
    asm("v_cvt_pk_bf16_f32 %0, %1, %2" : "=v"(u.w[3]) : "v"(b.z), "v"(b.w));
    return u.v;
}

// ---------------- weight fusion (pre-transposed bf16, both padded to [64][512]) ----------------
__global__ void fuse_k(const float* __restrict__ wf, const float* __restrict__ bf,
                       const float* __restrict__ wt, const float* __restrict__ bt,
                       const float* __restrict__ w1,
                       ushort_t* __restrict__ WfxT, ushort_t* __restrict__ WtxT,
                       float* __restrict__ bpre) {
    const int idx = blockIdx.x * 256 + threadIdx.x;
    const int T1 = H * KP;
    const int T2 = 2 * T1;
    if (idx < T1) {
        const int c = idx >> 9, k = idx & 511;
        float s = 0.f;
        if (k < K_FEAT) {
            #pragma unroll 8
            for (int u = 0; u < 64; ++u) s = fmaf(wf[k * 64 + u], w1[u * 64 + c], s);
        }
        WfxT[idx] = f2bf(s);
    } else if (idx < T2) {
        const int r = idx - T1;
        const int c = r >> 9, k = r & 511;
        float s = 0.f;
        if (k < K_TEXT) {
            #pragma unroll 8
            for (int u = 0; u < 64; ++u) s = fmaf(wt[k * 64 + u], w1[(64 + u) * 64 + c], s);
        }
        WtxT[r] = f2bf(s);
    } else if (idx < T2 + H) {
        const int j = idx - T2;
        float s = 0.f;
        for (int u = 0; u < 64; ++u) s = fmaf(bf[u], w1[u * 64 + j], s);
        for (int u = 0; u < 64; ++u) s = fmaf(bt[u], w1[(64 + u) * 64 + j], s);
        bpre[j] = s;
    }
}

// ---------------- degree (edge count per dst) ----------------
__global__ void deg_k(const int* __restrict__ ei, int* __restrict__ deg) {
    const int e = blockIdx.x * 256 + threadIdx.x;
    if (e < NE) atomicAdd(&deg[ei[NE + e]], 1);
}

// ---------------- CSR build ----------------
__global__ __launch_bounds__(256)
void partial_k(const int* __restrict__ deg, int* __restrict__ partial) {
    const int b = blockIdx.x;
    const int base = b * NODES_PER_SCAN;
    const int t = threadIdx.x;
    int s = 0;
    for (int i = t; i < NODES_PER_SCAN; i += 256) s += deg[base + i];
    #pragma unroll
    for (int m = 1; m < 64; m <<= 1) s += __shfl_xor(s, m, 64);
    __shared__ int ws[4];
    if ((t & 63) == 0) ws[t >> 6] = s;
    __syncthreads();
    if (t == 0) partial[b] = ws[0] + ws[1] + ws[2] + ws[3];
}

__global__ void scanp_k(const int* __restrict__ partial, int* __restrict__ psum) {
    __shared__ int buf[SCAN_BLOCKS];
    const int t = threadIdx.x;
    if (t < SCAN_BLOCKS) buf[t] = partial[t];
    __syncthreads();
    if (t == 0) {
        int run = 0;
        for (int i = 0; i < SCAN_BLOCKS; ++i) { int v = buf[i]; buf[i] = run; run += v; }
    }
    __syncthreads();
    if (t < SCAN_BLOCKS) psum[t] = buf[t];
}

// offsets + cursor + dinv (dinv folded in: reads deg anyway)
__global__ __launch_bounds__(256)
void offsets_k(const int* __restrict__ deg, const int* __restrict__ psum,
               int* __restrict__ row_start, int* __restrict__ cursor,
               float* __restrict__ dinv) {
    const int b = blockIdx.x;
    const int base = b * NODES_PER_SCAN;
    const int t = threadIdx.x;
    __shared__ int tsum[256];
    int loc[4];
    int dg[4];
    int s = 0;
    #pragma unroll
    for (int i = 0; i < 4; ++i) {
        loc[i] = s;
        const int n = t * 4 + i;
        dg[i] = (n < NODES_PER_SCAN) ? deg[base + n] : 0;
        s += dg[i];
    }
    tsum[t] = s;
    __syncthreads();
    #pragma unroll
    for (int off = 1; off < 256; off <<= 1) {
        int v = (t >= off) ? tsum[t - off] : 0;
        __syncthreads();
        tsum[t] += v;
        __syncthreads();
    }
    const int texcl = (t == 0) ? 0 : tsum[t - 1];
    const int bp = psum[b];
    #pragma unroll
    for (int i = 0; i < 4; ++i) {
        const int n = t * 4 + i;
        if (n < NODES_PER_SCAN) {
            const int rs = bp + texcl + loc[i];
            row_start[base + n] = rs;
            cursor[base + n] = rs;
            dinv[base + n] = rsqrtf((float)dg[i] + 1.0f);
        }
    }
}

__global__ void sort_k(const int* __restrict__ ei, int* __restrict__ cursor,
                       int* __restrict__ src_sorted) {
    const int e = blockIdx.x * 256 + threadIdx.x;
    if (e < NE) {
        const int s = ei[e];
        const int d = ei[NE + e];
        const int pos = atomicAdd(&cursor[d], 1);
        src_sorted[pos] = s;
    }
}

// ---------------- GEMM1 (MFMA bf16, LDS-free, 2-deep pipelined streaming A) ----------------
// u1[N,64] = (x@Wfx + txt@Wtx + bpre) * dinv[row]
// 4 independent waves/block, wave owns 32 rows. B fragments read directly from
// global (64/48 KB, L2-resident). A read per-lane coalesced (4 lanes x 32B cover
// one row's 128B k-chunk), converted in-register via v_cvt_pk_bf16_f32.
// No LDS, no barriers -> occupancy VGPR-bound, loads pipeline freely.
__global__ __launch_bounds__(256)
void gemm1_mfma(const float* __restrict__ x, const float* __restrict__ txt,
                const ushort_t* __restrict__ WfxT, const ushort_t* __restrict__ WtxT,
                const float* __restrict__ bpre, const float* __restrict__ dinv,
                float* __restrict__ u1) {
    const int t = threadIdx.x;
    const int wave = t >> 6, lane = t & 63;
    const int row0 = blockIdx.x * BM;
    const int lr = lane & 15;
    const int lq = lane >> 4;           // 0..3 -> k sub-offset lq*8

    f32x4 acc[2][4];
    #pragma unroll
    for (int i = 0; i < 2; ++i)
        #pragma unroll
        for (int j = 0; j < 4; ++j) acc[i][j] = (f32x4){0.f, 0.f, 0.f, 0.f};

    int rowi[2];
    rowi[0] = min(row0 + wave * 32 + lr, NN - 1);
    rowi[1] = min(row0 + wave * 32 + 16 + lr, NN - 1);

    auto phase = [&](const float* __restrict__ A, const ushort_t* __restrict__ WT,
                     auto KD, auto NT) {
        constexpr int KDIM = decltype(KD)::value;
        constexpr int NTILE = decltype(NT)::value;
        const float* p0 = A + (long)rowi[0] * KDIM + lq * 8;
        const float* p1 = A + (long)rowi[1] * KDIM + lq * 8;

        float4 buf[2][2][2][2];   // [pipe][rf][ks][ch] — all indices static (full unroll)

        auto loadA = [&](int pipe, int kt) {   // kt is compile-time under full unroll
            #pragma unroll
            for (int rf = 0; rf < 2; ++rf) {
                const float* p = rf ? p1 : p0;
                #pragma unroll
                for (int ks = 0; ks < 2; ++ks)
                    #pragma unroll
                    for (int ch = 0; ch < 2; ++ch) {
                        const int k = kt * 64 + ks * 32 + ch * 4;
                        if (KDIM % 64 == 0 || kt < NTILE - 1) {
                            buf[pipe][rf][ks][ch] = *(const float4*)(p + k);
                        } else {
                            buf[pipe][rf][ks][ch] = (k + lq * 8 < KDIM)
                                ? *(const float4*)(p + k)
                                : make_float4(0.f, 0.f, 0.f, 0.f);
                        }
                    }
            }
        };

        loadA(0, 0);
        #pragma unroll
        for (int kt = 0; kt < NTILE; ++kt) {
            if (kt + 1 < NTILE) loadA((kt + 1) & 1, kt + 1);
            #pragma unroll
            for (int ks = 0; ks < 2; ++ks) {
                bf16x8 bfr[4];
                #pragma unroll
                for (int cf = 0; cf < 4; ++cf)
                    bfr[cf] = *(const bf16x8*)(WT + (long)(cf * 16 + lr) * KP
                                               + kt * 64 + ks * 32 + lq * 8);
                bf16x8 af[2];
                #pragma unroll
                for (int rf = 0; rf < 2; ++rf)
                    af[rf] = cvt8(buf[kt & 1][rf][ks][0], buf[kt & 1][rf][ks][1]);
                #pragma unroll
                for (int rf = 0; rf < 2; ++rf)
                    #pragma unroll
                    for (int cf = 0; cf < 4; ++cf)
                        acc[rf][cf] = __builtin_amdgcn_mfma_f32_16x16x32_bf16(
                            af[rf], bfr[cf], acc[rf][cf], 0, 0, 0);
            }
        }
    };

    phase(x, WfxT, IC<K_FEAT>{}, IC<8>{});
    phase(txt, WtxT, IC<K_TEXT>{}, IC<6>{});

    // epilogue: D frag layout col=lane&15, row=(lane>>4)*4+reg
    #pragma unroll
    for (int rf = 0; rf < 2; ++rf) {
        #pragma unroll
        for (int reg = 0; reg < 4; ++reg) {
            const int r = row0 + wave * 32 + rf * 16 + lq * 4 + reg;
            if (r < NN) {
                const float di = dinv[r];
                #pragma unroll
                for (int cf = 0; cf < 4; ++cf) {
                    const int c = cf * 16 + lr;
                    u1[(long)r * H + c] = (acc[rf][cf][reg] + bpre[c]) * di;
                }
            }
        }
    }
}

// ---------------- layer1: CSR gather-aggregate + relu + 64->7 projection ----------------
__global__ __launch_bounds__(256)
void layer1_csr_k(const int* __restrict__ row_start, const int* __restrict__ deg,
                  const int* __restrict__ src_sorted, const float* __restrict__ u1,
                  const float* __restrict__ dinv, const float* __restrict__ b1,
                  const float* __restrict__ w2, float* __restrict__ u2) {
    const int t = threadIdx.x;
    const int lane = t & 63;
    const int node = blockIdx.x * 4 + (t >> 6);
    if (node >= NN) return;
    const int rs = row_start[node];
    const int dg = deg[node];
    float acc = u1[(long)node * H + lane];   // self
    for (int j0 = 0; j0 < dg; j0 += 64) {
        const int nj = min(64, dg - j0);
        int sv = 0;
        if (lane < nj) sv = src_sorted[rs + j0 + lane];
        int j = 0;
        for (; j + 4 <= nj; j += 4) {
            const int s0 = __shfl(sv, j, 64);
            const int s1 = __shfl(sv, j + 1, 64);
            const int s2 = __shfl(sv, j + 2, 64);
            const int s3 = __shfl(sv, j + 3, 64);
            const float v0 = u1[(long)s0 * H + lane];
            const float v1 = u1[(long)s1 * H + lane];
            const float v2 = u1[(long)s2 * H + lane];
            const float v3 = u1[(long)s3 * H + lane];
            acc += v0; acc += v1; acc += v2; acc += v3;
        }
        for (; j < nj; ++j) {
            const int s = __shfl(sv, j, 64);
            acc += u1[(long)s * H + lane];
        }
    }
    const float di = dinv[node];
    const float h = fmaxf(di * acc + b1[lane], 0.f);
    #pragma unroll
    for (int j = 0; j < 7; ++j) {
        float s = h * w2[lane * 7 + j];
        #pragma unroll
        for (int m = 1; m < 64; m <<= 1) s += __shfl_xor(s, m, 64);
        if (lane == j) u2[node * 8 + j] = di * s;
    }
}

// ---------------- layer2: CSR gather-aggregate + final transform ----------------
__global__ __launch_bounds__(256)
void layer2_csr_k(const int* __restrict__ row_start, const int* __restrict__ deg,
                  const int* __restrict__ src_sorted, const float* __restrict__ u2,
                  const float* __restrict__ dinv, const float* __restrict__ b2,
                  float* __restrict__ out) {
    const int t = threadIdx.x;
    const int c = t & 7;
    const int node = blockIdx.x * 32 + (t >> 3);
    if (node >= NN) return;
    const int rs = row_start[node];
    const int dg = deg[node];
    float acc = (c < 7) ? u2[node * 8 + c] : 0.f;   // self
    int j = 0;
    for (; j + 4 <= dg; j += 4) {
        const int s0 = src_sorted[rs + j];
        const int s1 = src_sorted[rs + j + 1];
        const int s2 = src_sorted[rs + j + 2];
        const int s3 = src_sorted[rs + j + 3];
        if (c < 7) {
            acc += u2[s0 * 8 + c];
            acc += u2[s1 * 8 + c];
            acc += u2[s2 * 8 + c];
            acc += u2[s3 * 8 + c];
        }
    }
    for (; j < dg; ++j) {
        const int s = src_sorted[rs + j];
        if (c < 7) acc += u2[s * 8 + c];
    }
    if (c < 7) out[node * 7 + c] = dinv[node] * acc + b2[c];
}

extern "C" void kernel_launch(void* const* d_in, const int* in_sizes, int n_in,
                              void* d_out, int out_size, void* d_ws, size_t ws_size,
                              hipStream_t stream) {
    const float* x      = (const float*)d_in[0];
    const float* txt    = (const float*)d_in[1];
    const int*   ei     = (const int*)d_in[2];
    const float* w_feat = (const float*)d_in[3];
    const float* b_feat = (const float*)d_in[4];
    const float* w_text = (const float*)d_in[5];
    const float* b_text = (const float*)d_in[6];
    const float* w1     = (const float*)d_in[7];
    const float* b1     = (const float*)d_in[8];
    const float* w2     = (const float*)d_in[9];
    const float* b2     = (const float*)d_in[10];
    float* out = (float*)d_out;

    char* p = (char*)d_ws;
    auto alloc = [&](size_t bytes) {
        char* r = p;
        p += (bytes + 255) & ~(size_t)255;
        return r;
    };
    ushort_t* WfxT = (ushort_t*)alloc((size_t)H * KP * 2);
    ushort_t* WtxT = (ushort_t*)alloc((size_t)H * KP * 2);
    float* bpre = (float*)alloc(H * 4);
    int*   deg  = (int*)alloc((size_t)NN * 4);
    float* dinv = (float*)alloc((size_t)NN * 4);
    int*   row_start = (int*)alloc((size_t)NN * 4);
    int*   cursor    = (int*)alloc((size_t)NN * 4);
    int*   partial   = (int*)alloc((size_t)SCAN_BLOCKS * 4);
    int*   psum      = (int*)alloc((size_t)SCAN_BLOCKS * 4);
    int*   src_sorted = (int*)alloc((size_t)NE * 4);
    float* u1   = (float*)alloc((size_t)NN * H * 4);
    float* u2   = (float*)alloc((size_t)NN * 8 * 4);

    hipMemsetAsync(deg, 0, (size_t)NN * 4, stream);

    const int fuse_tot = 2 * H * KP + H;
    fuse_k<<<(fuse_tot + 255) / 256, 256, 0, stream>>>(w_feat, b_feat, w_text, b_text, w1,
                                                       WfxT, WtxT, bpre);
    deg_k<<<(NE + 255) / 256, 256, 0, stream>>>(ei, deg);
    partial_k<<<SCAN_BLOCKS, 256, 0, stream>>>(deg, partial);
    scanp_k<<<1, 128, 0, stream>>>(partial, psum);
    offsets_k<<<SCAN_BLOCKS, 256, 0, stream>>>(deg, psum, row_start, cursor, dinv);
    sort_k<<<(NE + 255) / 256, 256, 0, stream>>>(ei, cursor, src_sorted);
    gemm1_mfma<<<(NN + BM - 1) / BM, 256, 0, stream>>>(x, txt, WfxT, WtxT, bpre, dinv, u1);
    layer1_csr_k<<<(NN + 3) / 4, 256, 0, stream>>>(row_start, deg, src_sorted, u1,
                                                   dinv, b1, w2, u2);
    layer2_csr_k<<<(NN + 31) / 32, 256, 0, stream>>>(row_start, deg, src_sorted, u2,
                                                     dinv, b2, out);
}

// Round 6
// 396.597 us; speedup vs baseline: 1.0580x; 1.0580x over previous
//
#include <hip/hip_runtime.h>

#define NN 100000
#define NE 1280000
#define K_FEAT 500
#define K_TEXT 384
#define KP 512
#define H 64
#define BM 128
#define BK 64
#define SCAN_BLOCKS 100
#define NODES_PER_SCAN 1000

typedef unsigned short ushort_t;
typedef __attribute__((ext_vector_type(8))) short bf16x8;
typedef __attribute__((ext_vector_type(4))) float f32x4;

template <int V> struct IC { static constexpr int value = V; };

__device__ __forceinline__ ushort_t f2bf(float f) {
    union { float f; unsigned int u; } v; v.f = f;
    unsigned int r = (v.u + 0x7FFFu + ((v.u >> 16) & 1u)) >> 16;  // RNE
    return (ushort_t)r;
}

// pack 8 f32 -> 8 bf16 via hardware cvt_pk (RNE)
__device__ __forceinline__ bf16x8 cvt8(float4 a, float4 b) {
    union { bf16x8 v; unsigned int w[4]; } u;
    asm("v_cvt_pk_bf16_f32 %0, %1, %2" : "=v"(u.w[0]) : "v"(a.x), "v"(a.y));
    asm("v_cvt_pk_bf16_f32 %0, %1, %2" : "=v"(u.w[1]) : "v"(a.z), "v"(a.w));
    asm("v_cvt_pk_bf16_f32 %0, %1, %2" : "=v"(u.w[2]) : "v"(b.x), "v"(b.y));
    asm("v_cvt_pk_bf16_f32 %0, %1, %2" : "=v"(u.w[3]) : "v"(b.z), "v"(b.w));
    return u.v;
}

// ---------------- weight fusion (pre-transposed bf16, both padded to [64][512]) ----------------
__global__ void fuse_k(const float* __restrict__ wf, const float* __restrict__ bf,
                       const float* __restrict__ wt, const float* __restrict__ bt,
                       const float* __restrict__ w1,
                       ushort_t* __restrict__ WfxT, ushort_t* __restrict__ WtxT,
                       float* __restrict__ bpre) {
    const int idx = blockIdx.x * 256 + threadIdx.x;
    const int T1 = H * KP;
    const int T2 = 2 * T1;
    if (idx < T1) {
        const int c = idx >> 9, k = idx & 511;
        float s = 0.f;
        if (k < K_FEAT) {
            #pragma unroll 8
            for (int u = 0; u < 64; ++u) s = fmaf(wf[k * 64 + u], w1[u * 64 + c], s);
        }
        WfxT[idx] = f2bf(s);
    } else if (idx < T2) {
        const int r = idx - T1;
        const int c = r >> 9, k = r & 511;
        float s = 0.f;
        if (k < K_TEXT) {
            #pragma unroll 8
            for (int u = 0; u < 64; ++u) s = fmaf(wt[k * 64 + u], w1[(64 + u) * 64 + c], s);
        }
        WtxT[r] = f2bf(s);
    } else if (idx < T2 + H) {
        const int j = idx - T2;
        float s = 0.f;
        for (int u = 0; u < 64; ++u) s = fmaf(bf[u], w1[u * 64 + j], s);
        for (int u = 0; u < 64; ++u) s = fmaf(bt[u], w1[(64 + u) * 64 + j], s);
        bpre[j] = s;
    }
}

// ---------------- degree (edge count per dst) ----------------
__global__ void deg_k(const int* __restrict__ ei, int* __restrict__ deg) {
    const int e = blockIdx.x * 256 + threadIdx.x;
    if (e < NE) atomicAdd(&deg[ei[NE + e]], 1);
}

// ---------------- CSR build ----------------
__global__ __launch_bounds__(256)
void partial_k(const int* __restrict__ deg, int* __restrict__ partial) {
    const int b = blockIdx.x;
    const int base = b * NODES_PER_SCAN;
    const int t = threadIdx.x;
    int s = 0;
    for (int i = t; i < NODES_PER_SCAN; i += 256) s += deg[base + i];
    #pragma unroll
    for (int m = 1; m < 64; m <<= 1) s += __shfl_xor(s, m, 64);
    __shared__ int ws[4];
    if ((t & 63) == 0) ws[t >> 6] = s;
    __syncthreads();
    if (t == 0) partial[b] = ws[0] + ws[1] + ws[2] + ws[3];
}

__global__ void scanp_k(const int* __restrict__ partial, int* __restrict__ psum) {
    __shared__ int buf[SCAN_BLOCKS];
    const int t = threadIdx.x;
    if (t < SCAN_BLOCKS) buf[t] = partial[t];
    __syncthreads();
    if (t == 0) {
        int run = 0;
        for (int i = 0; i < SCAN_BLOCKS; ++i) { int v = buf[i]; buf[i] = run; run += v; }
    }
    __syncthreads();
    if (t < SCAN_BLOCKS) psum[t] = buf[t];
}

// offsets + cursor + dinv (dinv folded in: reads deg anyway)
__global__ __launch_bounds__(256)
void offsets_k(const int* __restrict__ deg, const int* __restrict__ psum,
               int* __restrict__ row_start, int* __restrict__ cursor,
               float* __restrict__ dinv) {
    const int b = blockIdx.x;
    const int base = b * NODES_PER_SCAN;
    const int t = threadIdx.x;
    __shared__ int tsum[256];
    int loc[4];
    int dg[4];
    int s = 0;
    #pragma unroll
    for (int i = 0; i < 4; ++i) {
        loc[i] = s;
        const int n = t * 4 + i;
        dg[i] = (n < NODES_PER_SCAN) ? deg[base + n] : 0;
        s += dg[i];
    }
    tsum[t] = s;
    __syncthreads();
    #pragma unroll
    for (int off = 1; off < 256; off <<= 1) {
        int v = (t >= off) ? tsum[t - off] : 0;
        __syncthreads();
        tsum[t] += v;
        __syncthreads();
    }
    const int texcl = (t == 0) ? 0 : tsum[t - 1];
    const int bp = psum[b];
    #pragma unroll
    for (int i = 0; i < 4; ++i) {
        const int n = t * 4 + i;
        if (n < NODES_PER_SCAN) {
            const int rs = bp + texcl + loc[i];
            row_start[base + n] = rs;
            cursor[base + n] = rs;
            dinv[base + n] = rsqrtf((float)dg[i] + 1.0f);
        }
    }
}

__global__ void sort_k(const int* __restrict__ ei, int* __restrict__ cursor,
                       int* __restrict__ src_sorted) {
    const int e = blockIdx.x * 256 + threadIdx.x;
    if (e < NE) {
        const int s = ei[e];
        const int d = ei[NE + e];
        const int pos = atomicAdd(&cursor[d], 1);
        src_sorted[pos] = s;
    }
}

// ---------------- GEMM1 (MFMA bf16, global_load_lds DMA-staged A) ----------------
// u1[N,64] = (x@Wfx + txt@Wtx + bpre) * dinv[row]
// Single-buffered 128x64 fp32 A tile staged via global_load_lds (32 KB in flight
// per staging block, decoupled from VGPRs). LDS layout XOR-swizzled via
// pre-swizzled SOURCE addresses (rule #21: swizzle both sides or neither).
// B fragments read per-lane from global (64 KB, L2-resident). Tail-K handled by
// clamping the source chunk: fetched garbage multiplies zero-padded B columns.
__global__ __launch_bounds__(256)
void gemm1_mfma(const float* __restrict__ x, const float* __restrict__ txt,
                const ushort_t* __restrict__ WfxT, const ushort_t* __restrict__ WtxT,
                const float* __restrict__ bpre, const float* __restrict__ dinv,
                float* __restrict__ u1) {
    __shared__ float As[BM * BK];       // 32 KB, phys = logical ^ ((row&7)<<4) on bytes 4..6
    char* const ldsc = (char*)As;
    const int t = threadIdx.x;
    const int wave = t >> 6, lane = t & 63;
    const int row0 = blockIdx.x * BM;
    const int lr = lane & 15;
    const int lq = lane >> 4;           // 0..3 -> k sub-offset lq*8

    f32x4 acc[2][4];
    #pragma unroll
    for (int i = 0; i < 2; ++i)
        #pragma unroll
        for (int j = 0; j < 4; ++j) acc[i][j] = (f32x4){0.f, 0.f, 0.f, 0.f};

    // DMA stage one 128x64 fp32 tile (k0..k0+63) with pre-swizzled global source.
    auto stage = [&](const float* __restrict__ A, const int Kdim, const int k0) {
        #pragma unroll
        for (int p = 0; p < 8; ++p) {
            const int P = p * 4096 + t * 16;                 // physical LDS byte
            const int row = P >> 8;                          // 256 B per row
            const int kk = ((((t & 15) * 16) ^ ((row & 7) << 4)) >> 2);  // logical float
            const int gk = min(k0 + kk, Kdim - 4);           // tail clamp (B pad is 0)
            const int grow = min(row0 + row, NN - 1);
            const float* src = A + (long)grow * Kdim + gk;
            __builtin_amdgcn_global_load_lds(
                (const __attribute__((address_space(1))) void*)src,
                (__attribute__((address_space(3))) void*)(ldsc + P),
                16, 0, 0);
        }
    };

    auto compute = [&](const ushort_t* __restrict__ WT, const int kt) {
        #pragma unroll
        for (int ks = 0; ks < 2; ++ks) {
            bf16x8 bfr[4];
            #pragma unroll
            for (int cf = 0; cf < 4; ++cf)
                bfr[cf] = *(const bf16x8*)(WT + (long)(cf * 16 + lr) * KP
                                           + kt * 64 + ks * 32 + lq * 8);
            bf16x8 af[2];
            #pragma unroll
            for (int rf = 0; rf < 2; ++rf) {
                const int r2 = wave * 32 + rf * 16 + lr;
                const int bl = r2 * 256 + ks * 128 + lq * 32;   // logical byte
                const int xr = (r2 & 7) << 4;
                const float4 c0 = *(const float4*)(ldsc + (bl ^ xr));
                const float4 c1 = *(const float4*)(ldsc + ((bl + 16) ^ xr));
                af[rf] = cvt8(c0, c1);
            }
            #pragma unroll
            for (int rf = 0; rf < 2; ++rf)
                #pragma unroll
                for (int cf = 0; cf < 4; ++cf)
                    acc[rf][cf] = __builtin_amdgcn_mfma_f32_16x16x32_bf16(
                        af[rf], bfr[cf], acc[rf][cf], 0, 0, 0);
        }
    };

    auto phase = [&](const float* __restrict__ A, const ushort_t* __restrict__ WT,
                     auto KD, auto NT_) {
        constexpr int KDIM = decltype(KD)::value;
        constexpr int NTILE = decltype(NT_)::value;
        stage(A, KDIM, 0);
        for (int kt = 0; kt < NTILE; ++kt) {
            __syncthreads();                 // drain DMA of tile kt
            compute(WT, kt);
            __syncthreads();                 // all waves done reading
            if (kt + 1 < NTILE) stage(A, KDIM, (kt + 1) * BK);
        }
    };

    phase(x, WfxT, IC<K_FEAT>{}, IC<8>{});
    phase(txt, WtxT, IC<K_TEXT>{}, IC<6>{});

    // epilogue: D frag layout col=lane&15, row=(lane>>4)*4+reg
    #pragma unroll
    for (int rf = 0; rf < 2; ++rf) {
        #pragma unroll
        for (int reg = 0; reg < 4; ++reg) {
            const int r = row0 + wave * 32 + rf * 16 + lq * 4 + reg;
            if (r < NN) {
                const float di = dinv[r];
                #pragma unroll
                for (int cf = 0; cf < 4; ++cf) {
                    const int c = cf * 16 + lr;
                    u1[(long)r * H + c] = (acc[rf][cf][reg] + bpre[c]) * di;
                }
            }
        }
    }
}

// ---------------- layer1: CSR gather-aggregate + relu + 64->7 projection ----------------
__global__ __launch_bounds__(256)
void layer1_csr_k(const int* __restrict__ row_start, const int* __restrict__ deg,
                  const int* __restrict__ src_sorted, const float* __restrict__ u1,
                  const float* __restrict__ dinv, const float* __restrict__ b1,
                  const float* __restrict__ w2, float* __restrict__ u2) {
    const int t = threadIdx.x;
    const int lane = t & 63;
    const int node = blockIdx.x * 4 + (t >> 6);
    if (node >= NN) return;
    const int rs = row_start[node];
    const int dg = deg[node];
    float acc = u1[(long)node * H + lane];   // self
    for (int j0 = 0; j0 < dg; j0 += 64) {
        const int nj = min(64, dg - j0);
        int sv = 0;
        if (lane < nj) sv = src_sorted[rs + j0 + lane];
        int j = 0;
        for (; j + 4 <= nj; j += 4) {
            const int s0 = __shfl(sv, j, 64);
            const int s1 = __shfl(sv, j + 1, 64);
            const int s2 = __shfl(sv, j + 2, 64);
            const int s3 = __shfl(sv, j + 3, 64);
            const float v0 = u1[(long)s0 * H + lane];
            const float v1 = u1[(long)s1 * H + lane];
            const float v2 = u1[(long)s2 * H + lane];
            const float v3 = u1[(long)s3 * H + lane];
            acc += v0; acc += v1; acc += v2; acc += v3;
        }
        for (; j < nj; ++j) {
            const int s = __shfl(sv, j, 64);
            acc += u1[(long)s * H + lane];
        }
    }
    const float di = dinv[node];
    const float h = fmaxf(di * acc + b1[lane], 0.f);
    #pragma unroll
    for (int j = 0; j < 7; ++j) {
        float s = h * w2[lane * 7 + j];
        #pragma unroll
        for (int m = 1; m < 64; m <<= 1) s += __shfl_xor(s, m, 64);
        if (lane == j) u2[node * 8 + j] = di * s;
    }
}

// ---------------- layer2: CSR gather-aggregate + final transform ----------------
__global__ __launch_bounds__(256)
void layer2_csr_k(const int* __restrict__ row_start, const int* __restrict__ deg,
                  const int* __restrict__ src_sorted, const float* __restrict__ u2,
                  const float* __restrict__ dinv, const float* __restrict__ b2,
                  float* __restrict__ out) {
    const int t = threadIdx.x;
    const int c = t & 7;
    const int node = blockIdx.x * 32 + (t >> 3);
    if (node >= NN) return;
    const int rs = row_start[node];
    const int dg = deg[node];
    float acc = (c < 7) ? u2[node * 8 + c] : 0.f;   // self
    int j = 0;
    for (; j + 4 <= dg; j += 4) {
        const int s0 = src_sorted[rs + j];
        const int s1 = src_sorted[rs + j + 1];
        const int s2 = src_sorted[rs + j + 2];
        const int s3 = src_sorted[rs + j + 3];
        if (c < 7) {
            acc += u2[s0 * 8 + c];
            acc += u2[s1 * 8 + c];
            acc += u2[s2 * 8 + c];
            acc += u2[s3 * 8 + c];
        }
    }
    for (; j < dg; ++j) {
        const int s = src_sorted[rs + j];
        if (c < 7) acc += u2[s * 8 + c];
    }
    if (c < 7) out[node * 7 + c] = dinv[node] * acc + b2[c];
}

extern "C" void kernel_launch(void* const* d_in, const int* in_sizes, int n_in,
                              void* d_out, int out_size, void* d_ws, size_t ws_size,
                              hipStream_t stream) {
    const float* x      = (const float*)d_in[0];
    const float* txt    = (const float*)d_in[1];
    const int*   ei     = (const int*)d_in[2];
    const float* w_feat = (const float*)d_in[3];
    const float* b_feat = (const float*)d_in[4];
    const float* w_text = (const float*)d_in[5];
    const float* b_text = (const float*)d_in[6];
    const float* w1     = (const float*)d_in[7];
    const float* b1     = (const float*)d_in[8];
    const float* w2     = (const float*)d_in[9];
    const float* b2     = (const float*)d_in[10];
    float* out = (float*)d_out;

    char* p = (char*)d_ws;
    auto alloc = [&](size_t bytes) {
        char* r = p;
        p += (bytes + 255) & ~(size_t)255;
        return r;
    };
    ushort_t* WfxT = (ushort_t*)alloc((size_t)H * KP * 2);
    ushort_t* WtxT = (ushort_t*)alloc((size_t)H * KP * 2);
    float* bpre = (float*)alloc(H * 4);
    int*   deg  = (int*)alloc((size_t)NN * 4);
    float* dinv = (float*)alloc((size_t)NN * 4);
    int*   row_start = (int*)alloc((size_t)NN * 4);
    int*   cursor    = (int*)alloc((size_t)NN * 4);
    int*   partial   = (int*)alloc((size_t)SCAN_BLOCKS * 4);
    int*   psum      = (int*)alloc((size_t)SCAN_BLOCKS * 4);
    int*   src_sorted = (int*)alloc((size_t)NE * 4);
    float* u1   = (float*)alloc((size_t)NN * H * 4);
    float* u2   = (float*)alloc((size_t)NN * 8 * 4);

    hipMemsetAsync(deg, 0, (size_t)NN * 4, stream);

    const int fuse_tot = 2 * H * KP + H;
    fuse_k<<<(fuse_tot + 255) / 256, 256, 0, stream>>>(w_feat, b_feat, w_text, b_text, w1,
                                                       WfxT, WtxT, bpre);
    deg_k<<<(NE + 255) / 256, 256, 0, stream>>>(ei, deg);
    partial_k<<<SCAN_BLOCKS, 256, 0, stream>>>(deg, partial);
    scanp_k<<<1, 128, 0, stream>>>(partial, psum);
    offsets_k<<<SCAN_BLOCKS, 256, 0, stream>>>(deg, psum, row_start, cursor, dinv);
    sort_k<<<(NE + 255) / 256, 256, 0, stream>>>(ei, cursor, src_sorted);
    gemm1_mfma<<<(NN + BM - 1) / BM, 256, 0, stream>>>(x, txt, WfxT, WtxT, bpre, dinv, u1);
    layer1_csr_k<<<(NN + 3) / 4, 256, 0, stream>>>(row_start, deg, src_sorted, u1,
                                                   dinv, b1, w2, u2);
    layer2_csr_k<<<(NN + 31) / 32, 256, 0, stream>>>(row_start, deg, src_sorted, u2,
                                                     dinv, b2, out);
}

// Round 7
// 365.245 us; speedup vs baseline: 1.1488x; 1.0858x over previous
//
#include <hip/hip_runtime.h>

#define NN 100000
#define NE 1280000
#define K_FEAT 500
#define K_TEXT 384
#define KP 512
#define H 64
#define BM 64
#define BKC 256            // k-span of one staged B chunk (4 K-tiles of 64)
#define SCAN_BLOCKS 100
#define NODES_PER_SCAN 1000

typedef unsigned short ushort_t;
typedef __attribute__((ext_vector_type(8))) short bf16x8;
typedef __attribute__((ext_vector_type(4))) float f32x4;

template <int V> struct IC { static constexpr int value = V; };

__device__ __forceinline__ ushort_t f2bf(float f) {
    union { float f; unsigned int u; } v; v.f = f;
    unsigned int r = (v.u + 0x7FFFu + ((v.u >> 16) & 1u)) >> 16;  // RNE
    return (ushort_t)r;
}

__device__ __forceinline__ float bf2f(ushort_t u) {
    union { unsigned int i; float f; } v; v.i = ((unsigned int)u) << 16; return v.f;
}

// pack 8 f32 -> 8 bf16 via hardware cvt_pk (RNE)
__device__ __forceinline__ bf16x8 cvt8(float4 a, float4 b) {
    union { bf16x8 v; unsigned int w[4]; } u;
    asm("v_cvt_pk_bf16_f32 %0, %1, %2" : "=v"(u.w[0]) : "v"(a.x), "v"(a.y));
    asm("v_cvt_pk_bf16_f32 %0, %1, %2" : "=v"(u.w[1]) : "v"(a.z), "v"(a.w));
    asm("v_cvt_pk_bf16_f32 %0, %1, %2" : "=v"(u.w[2]) : "v"(b.x), "v"(b.y));
    asm("v_cvt_pk_bf16_f32 %0, %1, %2" : "=v"(u.w[3]) : "v"(b.z), "v"(b.w));
    return u.v;
}

// ---------------- weight fusion (pre-transposed bf16, both padded to [64][512]) ----------------
__global__ void fuse_k(const float* __restrict__ wf, const float* __restrict__ bf,
                       const float* __restrict__ wt, const float* __restrict__ bt,
                       const float* __restrict__ w1,
                       ushort_t* __restrict__ WfxT, ushort_t* __restrict__ WtxT,
                       float* __restrict__ bpre) {
    const int idx = blockIdx.x * 256 + threadIdx.x;
    const int T1 = H * KP;
    const int T2 = 2 * T1;
    if (idx < T1) {
        const int c = idx >> 9, k = idx & 511;
        float s = 0.f;
        if (k < K_FEAT) {
            #pragma unroll 8
            for (int u = 0; u < 64; ++u) s = fmaf(wf[k * 64 + u], w1[u * 64 + c], s);
        }
        WfxT[idx] = f2bf(s);
    } else if (idx < T2) {
        const int r = idx - T1;
        const int c = r >> 9, k = r & 511;
        float s = 0.f;
        if (k < K_TEXT) {
            #pragma unroll 8
            for (int u = 0; u < 64; ++u) s = fmaf(wt[k * 64 + u], w1[(64 + u) * 64 + c], s);
        }
        WtxT[r] = f2bf(s);
    } else if (idx < T2 + H) {
        const int j = idx - T2;
        float s = 0.f;
        for (int u = 0; u < 64; ++u) s = fmaf(bf[u], w1[u * 64 + j], s);
        for (int u = 0; u < 64; ++u) s = fmaf(bt[u], w1[(64 + u) * 64 + j], s);
        bpre[j] = s;
    }
}

// ---------------- degree (edge count per dst) ----------------
__global__ void deg_k(const int* __restrict__ ei, int* __restrict__ deg) {
    const int e = blockIdx.x * 256 + threadIdx.x;
    if (e < NE) atomicAdd(&deg[ei[NE + e]], 1);
}

// ---------------- CSR build ----------------
__global__ __launch_bounds__(256)
void partial_k(const int* __restrict__ deg, int* __restrict__ partial) {
    const int b = blockIdx.x;
    const int base = b * NODES_PER_SCAN;
    const int t = threadIdx.x;
    int s = 0;
    for (int i = t; i < NODES_PER_SCAN; i += 256) s += deg[base + i];
    #pragma unroll
    for (int m = 1; m < 64; m <<= 1) s += __shfl_xor(s, m, 64);
    __shared__ int ws[4];
    if ((t & 63) == 0) ws[t >> 6] = s;
    __syncthreads();
    if (t == 0) partial[b] = ws[0] + ws[1] + ws[2] + ws[3];
}

__global__ void scanp_k(const int* __restrict__ partial, int* __restrict__ psum) {
    __shared__ int buf[SCAN_BLOCKS];
    const int t = threadIdx.x;
    if (t < SCAN_BLOCKS) buf[t] = partial[t];
    __syncthreads();
    if (t == 0) {
        int run = 0;
        for (int i = 0; i < SCAN_BLOCKS; ++i) { int v = buf[i]; buf[i] = run; run += v; }
    }
    __syncthreads();
    if (t < SCAN_BLOCKS) psum[t] = buf[t];
}

// offsets + cursor + dinv (dinv folded in: reads deg anyway)
__global__ __launch_bounds__(256)
void offsets_k(const int* __restrict__ deg, const int* __restrict__ psum,
               int* __restrict__ row_start, int* __restrict__ cursor,
               float* __restrict__ dinv) {
    const int b = blockIdx.x;
    const int base = b * NODES_PER_SCAN;
    const int t = threadIdx.x;
    __shared__ int tsum[256];
    int loc[4];
    int dg[4];
    int s = 0;
    #pragma unroll
    for (int i = 0; i < 4; ++i) {
        loc[i] = s;
        const int n = t * 4 + i;
        dg[i] = (n < NODES_PER_SCAN) ? deg[base + n] : 0;
        s += dg[i];
    }
    tsum[t] = s;
    __syncthreads();
    #pragma unroll
    for (int off = 1; off < 256; off <<= 1) {
        int v = (t >= off) ? tsum[t - off] : 0;
        __syncthreads();
        tsum[t] += v;
        __syncthreads();
    }
    const int texcl = (t == 0) ? 0 : tsum[t - 1];
    const int bp = psum[b];
    #pragma unroll
    for (int i = 0; i < 4; ++i) {
        const int n = t * 4 + i;
        if (n < NODES_PER_SCAN) {
            const int rs = bp + texcl + loc[i];
            row_start[base + n] = rs;
            cursor[base + n] = rs;
            dinv[base + n] = rsqrtf((float)dg[i] + 1.0f);
        }
    }
}

__global__ void sort_k(const int* __restrict__ ei, int* __restrict__ cursor,
                       int* __restrict__ src_sorted) {
    const int e = blockIdx.x * 256 + threadIdx.x;
    if (e < NE) {
        const int s = ei[e];
        const int d = ei[NE + e];
        const int pos = atomicAdd(&cursor[d], 1);
        src_sorted[pos] = s;
    }
}

// ---------------- GEMM1 (MFMA bf16): u1b[N,64] = bf16((x@Wfx + txt@Wtx + bpre) * dinv) ----
// BM=64 -> 1563 blocks; 4 waves x 16 rows. B staged per 32KB chunk (4 K-tiles) into
// XOR-swizzled LDS via reg->ds_write (coalesced-on-both-sides; 2-way conflicts = free).
// A read per-lane direct to VGPR (coalesced), cvt to bf16 in-register. Only 32KB LDS
// -> ~5 blocks/CU -> ~20 waves/CU for latency hiding; B reads off the TCP entirely.
__global__ __launch_bounds__(256, 4)
void gemm1_mfma(const float* __restrict__ x, const float* __restrict__ txt,
                const ushort_t* __restrict__ WfxT, const ushort_t* __restrict__ WtxT,
                const float* __restrict__ bpre, const float* __restrict__ dinv,
                ushort_t* __restrict__ u1b) {
    __shared__ ushort_t Bs[H * BKC];    // 32 KB, [col][k_local], 512B rows, XOR-swizzled
    char* const ldsb = (char*)Bs;
    const int t = threadIdx.x;
    const int wave = t >> 6, lane = t & 63;
    const int row0 = blockIdx.x * BM;
    const int lr = lane & 15, lq = lane >> 4;

    f32x4 acc[4];
    #pragma unroll
    for (int j = 0; j < 4; ++j) acc[j] = (f32x4){0.f, 0.f, 0.f, 0.f};

    const int rowi = min(row0 + wave * 16 + lr, NN - 1);

    auto phase = [&](const float* __restrict__ A, const ushort_t* __restrict__ WT,
                     auto KD, auto NT_) {
        constexpr int KDIM = decltype(KD)::value;
        constexpr int NTILE = decltype(NT_)::value;            // 64-k tiles
        constexpr int NCHUNK = (NTILE + 3) / 4;
        const float* pa = A + (long)rowi * KDIM;
        for (int chk = 0; chk < NCHUNK; ++chk) {
            __syncthreads();                                   // prev chunk fully consumed
            // ---- stage B chunk: 64 rows x 256 k bf16 = 32 KB (8 x 16B per thread) ----
            #pragma unroll
            for (int i = 0; i < 8; ++i) {
                const int off = (t + i * 256) * 8;             // ushort index in chunk
                const int row = off >> 8;                      // 256 ushorts per row
                bf16x8 v = *(const bf16x8*)(WT + (long)row * KP + chk * BKC + (off & 255));
                *(bf16x8*)(ldsb + ((off * 2) ^ ((row & 7) << 4))) = v;
            }
            __syncthreads();                                   // chunk ready
            const int ntile_c = (chk == NCHUNK - 1) ? (NTILE - 4 * (NCHUNK - 1)) : 4;
            for (int kt = 0; kt < ntile_c; ++kt) {
                #pragma unroll
                for (int ks = 0; ks < 2; ++ks) {
                    const int k = chk * BKC + kt * 64 + ks * 32 + lq * 8;
                    const int k0 = min(k, KDIM - 4);
                    const int k1 = min(k + 4, KDIM - 4);
                    const float4 c0 = *(const float4*)(pa + k0);
                    const float4 c1 = *(const float4*)(pa + k1);
                    const bf16x8 af = cvt8(c0, c1);
                    bf16x8 bfr[4];
                    #pragma unroll
                    for (int cf = 0; cf < 4; ++cf) {
                        const int row = cf * 16 + lr;
                        const int bl = row * 512 + kt * 128 + ks * 64 + lq * 16;
                        bfr[cf] = *(const bf16x8*)(ldsb + (bl ^ ((row & 7) << 4)));
                    }
                    #pragma unroll
                    for (int cf = 0; cf < 4; ++cf)
                        acc[cf] = __builtin_amdgcn_mfma_f32_16x16x32_bf16(
                            af, bfr[cf], acc[cf], 0, 0, 0);
                }
            }
        }
    };

    phase(x, WfxT, IC<K_FEAT>{}, IC<8>{});
    phase(txt, WtxT, IC<K_TEXT>{}, IC<6>{});

    // epilogue: D frag layout col=lane&15, row=(lane>>4)*4+reg; store bf16
    #pragma unroll
    for (int reg = 0; reg < 4; ++reg) {
        const int r = row0 + wave * 16 + lq * 4 + reg;
        if (r < NN) {
            const float di = dinv[r];
            #pragma unroll
            for (int cf = 0; cf < 4; ++cf) {
                const int c = cf * 16 + lr;
                u1b[(long)r * H + c] = f2bf((acc[cf][reg] + bpre[c]) * di);
            }
        }
    }
}

// ---------------- layer1: CSR gather-aggregate (bf16 u1) + relu + 64->7 projection --------
__global__ __launch_bounds__(256)
void layer1_csr_k(const int* __restrict__ row_start, const int* __restrict__ deg,
                  const int* __restrict__ src_sorted, const ushort_t* __restrict__ u1b,
                  const float* __restrict__ dinv, const float* __restrict__ b1,
                  const float* __restrict__ w2, float* __restrict__ u2) {
    const int t = threadIdx.x;
    const int lane = t & 63;
    const int node = blockIdx.x * 4 + (t >> 6);
    if (node >= NN) return;
    const int rs = row_start[node];
    const int dg = deg[node];
    float acc = bf2f(u1b[(long)node * H + lane]);   // self
    for (int j0 = 0; j0 < dg; j0 += 64) {
        const int nj = min(64, dg - j0);
        int sv = 0;
        if (lane < nj) sv = src_sorted[rs + j0 + lane];
        int j = 0;
        for (; j + 4 <= nj; j += 4) {
            const int s0 = __shfl(sv, j, 64);
            const int s1 = __shfl(sv, j + 1, 64);
            const int s2 = __shfl(sv, j + 2, 64);
            const int s3 = __shfl(sv, j + 3, 64);
            const float v0 = bf2f(u1b[(long)s0 * H + lane]);
            const float v1 = bf2f(u1b[(long)s1 * H + lane]);
            const float v2 = bf2f(u1b[(long)s2 * H + lane]);
            const float v3 = bf2f(u1b[(long)s3 * H + lane]);
            acc += v0; acc += v1; acc += v2; acc += v3;
        }
        for (; j < nj; ++j) {
            const int s = __shfl(sv, j, 64);
            acc += bf2f(u1b[(long)s * H + lane]);
        }
    }
    const float di = dinv[node];
    const float h = fmaxf(di * acc + b1[lane], 0.f);
    #pragma unroll
    for (int j = 0; j < 7; ++j) {
        float s = h * w2[lane * 7 + j];
        #pragma unroll
        for (int m = 1; m < 64; m <<= 1) s += __shfl_xor(s, m, 64);
        if (lane == j) u2[node * 8 + j] = di * s;
    }
}

// ---------------- layer2: CSR gather-aggregate + final transform ----------------
__global__ __launch_bounds__(256)
void layer2_csr_k(const int* __restrict__ row_start, const int* __restrict__ deg,
                  const int* __restrict__ src_sorted, const float* __restrict__ u2,
                  const float* __restrict__ dinv, const float* __restrict__ b2,
                  float* __restrict__ out) {
    const int t = threadIdx.x;
    const int c = t & 7;
    const int node = blockIdx.x * 32 + (t >> 3);
    if (node >= NN) return;
    const int rs = row_start[node];
    const int dg = deg[node];
    float acc = (c < 7) ? u2[node * 8 + c] : 0.f;   // self
    int j = 0;
    for (; j + 4 <= dg; j += 4) {
        const int s0 = src_sorted[rs + j];
        const int s1 = src_sorted[rs + j + 1];
        const int s2 = src_sorted[rs + j + 2];
        const int s3 = src_sorted[rs + j + 3];
        if (c < 7) {
            acc += u2[s0 * 8 + c];
            acc += u2[s1 * 8 + c];
            acc += u2[s2 * 8 + c];
            acc += u2[s3 * 8 + c];
        }
    }
    for (; j < dg; ++j) {
        const int s = src_sorted[rs + j];
        if (c < 7) acc += u2[s * 8 + c];
    }
    if (c < 7) out[node * 7 + c] = dinv[node] * acc + b2[c];
}

extern "C" void kernel_launch(void* const* d_in, const int* in_sizes, int n_in,
                              void* d_out, int out_size, void* d_ws, size_t ws_size,
                              hipStream_t stream) {
    const float* x      = (const float*)d_in[0];
    const float* txt    = (const float*)d_in[1];
    const int*   ei     = (const int*)d_in[2];
    const float* w_feat = (const float*)d_in[3];
    const float* b_feat = (const float*)d_in[4];
    const float* w_text = (const float*)d_in[5];
    const float* b_text = (const float*)d_in[6];
    const float* w1     = (const float*)d_in[7];
    const float* b1     = (const float*)d_in[8];
    const float* w2     = (const float*)d_in[9];
    const float* b2     = (const float*)d_in[10];
    float* out = (float*)d_out;

    char* p = (char*)d_ws;
    auto alloc = [&](size_t bytes) {
        char* r = p;
        p += (bytes + 255) & ~(size_t)255;
        return r;
    };
    ushort_t* WfxT = (ushort_t*)alloc((size_t)H * KP * 2);
    ushort_t* WtxT = (ushort_t*)alloc((size_t)H * KP * 2);
    float* bpre = (float*)alloc(H * 4);
    int*   deg  = (int*)alloc((size_t)NN * 4);
    float* dinv = (float*)alloc((size_t)NN * 4);
    int*   row_start = (int*)alloc((size_t)NN * 4);
    int*   cursor    = (int*)alloc((size_t)NN * 4);
    int*   partial   = (int*)alloc((size_t)SCAN_BLOCKS * 4);
    int*   psum      = (int*)alloc((size_t)SCAN_BLOCKS * 4);
    int*   src_sorted = (int*)alloc((size_t)NE * 4);
    ushort_t* u1b = (ushort_t*)alloc((size_t)NN * H * 2);
    float* u2   = (float*)alloc((size_t)NN * 8 * 4);

    hipMemsetAsync(deg, 0, (size_t)NN * 4, stream);

    const int fuse_tot = 2 * H * KP + H;
    fuse_k<<<(fuse_tot + 255) / 256, 256, 0, stream>>>(w_feat, b_feat, w_text, b_text, w1,
                                                       WfxT, WtxT, bpre);
    deg_k<<<(NE + 255) / 256, 256, 0, stream>>>(ei, deg);
    partial_k<<<SCAN_BLOCKS, 256, 0, stream>>>(deg, partial);
    scanp_k<<<1, 128, 0, stream>>>(partial, psum);
    offsets_k<<<SCAN_BLOCKS, 256, 0, stream>>>(deg, psum, row_start, cursor, dinv);
    sort_k<<<(NE + 255) / 256, 256, 0, stream>>>(ei, cursor, src_sorted);
    gemm1_mfma<<<(NN + BM - 1) / BM, 256, 0, stream>>>(x, txt, WfxT, WtxT, bpre, dinv, u1b);
    layer1_csr_k<<<(NN + 3) / 4, 256, 0, stream>>>(row_start, deg, src_sorted, u1b,
                                                   dinv, b1, w2, u2);
    layer2_csr_k<<<(NN + 31) / 32, 256, 0, stream>>>(row_start, deg, src_sorted, u2,
                                                     dinv, b2, out);
}